// Round 5
// baseline (2105.403 us; speedup 1.0000x reference)
//
#include <hip/hip_runtime.h>
#include <hip/hip_bf16.h>

// EntropyResidualBlock: y1 = prelu(maskconv(x,w1)+b1); y2 = prelu(maskconv(y1,w2)+b2); out = y2 + x
// 13 live taps. Implicit GEMM with mfma_f32_32x32x16_bf16.
//   conv1: D[p][o] = sum X[p+d(t)][i]*W1[t][i][o]  (A=X,B=W);  conv2: D[o][p] (A=W,B=Y).
// Layouts: X/Y packed [n][kc=24 x 16ch][h+4][w+4][16] bf16 (halo-padded);
//          W packed [t][kc][o][16] bf16 (masked).
// Round-5: occupancy play. Per-wave tile 64p x 64o (acc 2x2 f32x16 = 64 regs) ->
// ~135 regs/wave, __launch_bounds__(256,3) => 3 waves/SIMD (3 blocks/CU, LDS 3x40960B).
// Block = 2h x 64w x 128o, 4 waves (wr=h-row, wc=o-half). LDS X tile dbuf 2 x 20,480B
// (4 rows x 80 cols x 16ch x 2hf), staged via global_load_lds (5 x 1KB per wave),
// wb global loads issued BEFORE stage block (clean in-order vmcnt). wb ring-3 (2 ahead),
// xa 1 ahead, setprio around MFMA quad. Halo-zero kernel instead of 412MB memsets.
// Xc in d_out (dead before conv2 writes d_out); ws: [Y][Wp1][Wp2].

#define C_CH 384
#define HH   256
#define WWD  512
#define NN   2
#define NKC  24                    // 16-channel chunks
#define PR   260
#define PC   516
#define ICS16 (PR * PC * 16)       // shorts per (n,kc) plane = 2,146,560
#define TC   80                    // staged cols per tile (68 needed, 80 => 20 x 1KB issues)
#define HFSH (4 * TC * 16)         // 5120 shorts per hf sub-plane
#define TSH  (2 * HFSH)            // 10240 shorts = 20,480 B per buffer

typedef __attribute__((ext_vector_type(8)))  short short8;
typedef __attribute__((ext_vector_type(16))) float f32x16;

typedef const __attribute__((address_space(1))) void* gas_t;
typedef __attribute__((address_space(3))) void* las_t;

__device__ inline unsigned short f2bf(float f) {
    union { float f; unsigned int u; } v; v.f = f;
    unsigned int r = v.u + 0x7FFFu + ((v.u >> 16) & 1u);
    return (unsigned short)(r >> 16);
}

// ---------------- weights -> bf16 wp[t][kc][o][16], masked ----------------
__global__ __launch_bounds__(256) void k_prepack(const float* __restrict__ w1, const float* __restrict__ w2,
                                                 unsigned short* __restrict__ wp1, unsigned short* __restrict__ wp2) {
    int idx = blockIdx.x * 256 + threadIdx.x;
    const int TOT = 13 * NKC * C_CH * 16;
    if (idx >= TOT) return;
    int iq = idx & 15;
    int o  = (idx >> 4) % C_CH;
    int kc = (idx / (16 * C_CH)) % NKC;
    int t  = idx / (16 * C_CH * NKC);
    int i  = kc * 16 + iq;
    int kh = t < 5 ? 0 : (t < 10 ? 1 : 2);
    int kw = t < 5 ? t : (t < 10 ? t - 5 : t - 10);
    bool keep = (t != 12) || ((i / 24) <= (o / 24));
    int src = ((o * C_CH + i) * 5 + kh) * 5 + kw;
    wp1[idx] = keep ? f2bf(w1[src]) : (unsigned short)0;
    wp2[idx] = keep ? f2bf(w2[src]) : (unsigned short)0;
}

// ---------------- zero the halo borders of both packed buffers ----------------
__global__ __launch_bounds__(256) void k_zero_halo(unsigned short* __restrict__ a, unsigned short* __restrict__ b) {
    int plane = blockIdx.x;            // 0..47 (n*NKC+kc)
    const short8 z = (short8){0,0,0,0,0,0,0,0};
    for (int bi = 0; bi < 2; ++bi) {
        unsigned short* p = (bi ? b : a) + (size_t)plane * ICS16;
        // top rows 0,1 + bottom rows 258,259: 4 rows x 516 cols x 2 q  = 4128 short8
        for (int i = threadIdx.x; i < 4128; i += 256) {
            int r4 = i / 1032;
            int rem = i - r4 * 1032;
            int row = r4 < 2 ? r4 : 254 + r4;
            *(short8*)&p[row * (PC * 16) + rem * 8] = z;
        }
        // side cols 0,1,514,515 for rows 2..257: 256 rows x 8 short8
        for (int i = threadIdx.x; i < 2048; i += 256) {
            int row = 2 + (i >> 3);
            int j = i & 7;
            int col = (j < 4) ? (j >> 1) : (512 + (j >> 1));
            int q = j & 1;
            *(short8*)&p[(row * PC + col) * 16 + q * 8] = z;
        }
    }
}

// ---------------- x NCHW fp32 -> padded 16ch-chunked bf16 ----------------
__global__ __launch_bounds__(256) void k_repack_x(const float* __restrict__ x, unsigned short* __restrict__ xc) {
    int bid = blockIdx.x;              // 4096 blocks: 64 w x 384 c for one (n,h)
    int w0 = (bid & 7) << 6;
    int h  = (bid >> 3) & 255;
    int n  = bid >> 11;
    int wi = threadIdx.x & 63;
    int cq = threadIdx.x >> 6;         // 0..3 (8 channels each)
    int w  = w0 + wi;
    int inb = n * C_CH * HH * WWD + h * WWD + w;
    for (int cc = 0; cc < 12; ++cc) {
        int c0 = cc * 32 + cq * 8;
        short8 outv;
        #pragma unroll
        for (int k = 0; k < 8; ++k) {
            float f = x[inb + (c0 + k) * (HH * WWD)];
            outv[k] = (short)f2bf(f);
        }
        int kc = cc * 2 + (cq >> 1);
        int oidx = (n * NKC + kc) * ICS16 + ((h + 2) * PC + (w + 2)) * 16 + (cq & 1) * 8;
        *(short8*)&xc[oidx] = outv;
    }
}

// ---------------- masked conv via 32x32x16 MFMA ----------------
// grid 6144 = 8 xcd x 768; 256 threads / 4 waves (wr = h-row 0/1, wc = o-half).
template<int SECOND>
__global__ __launch_bounds__(256, 3) void k_conv(const unsigned short* __restrict__ in,   // packed
                                                 const unsigned short* __restrict__ wp,
                                                 const float* __restrict__ bias,
                                                 const float* __restrict__ alpha,
                                                 const float* __restrict__ xres,
                                                 void* __restrict__ outp) {
    __shared__ __align__(16) unsigned short Xs[2][TSH];   // 2 x 20,480 B

    // XCD-contiguous; ob innermost so the 3 o-blocks sharing an X tile run together.
    int bid0 = blockIdx.x;
    int xcd = bid0 & 7;
    int j0  = bid0 >> 3;                 // 0..767
    int tile = xcd * 256 + j0 / 3;       // 0..2047
    int ob   = j0 % 3;
    int wseg = tile & 7;
    int hp   = (tile >> 3) & 127;
    int n    = tile >> 10;
    int w0 = wseg << 6, o0 = ob << 7, h0 = hp << 1;

    int tid = threadIdx.x;
    int lane = tid & 63;
    int wv = tid >> 6;
    int wr = wv >> 1, wc = wv & 1;
    int lo5 = lane & 31, hi = lane >> 5;

    // 20 staging wave-issues per buffer, 5 per wave; per-lane global offsets (shorts)
    int goff[5];
    #pragma unroll
    for (int it = 0; it < 5; ++it) {
        int k = wv * 5 + it;             // 0..19
        int s = k * 64 + lane;           // 16B slot 0..1279
        int hf = s / 640;
        int rem = s - hf * 640;
        int row = rem / 160;
        int rem2 = rem - row * 160;
        int col = rem2 >> 1, q = rem2 & 1;
        goff[it] = hf * ICS16 + ((h0 + row) * PC + (w0 + col)) * 16 + q * 8;
    }

    const int KH[13] = {0,0,0,0,0,1,1,1,1,1,2,2,2};
    const int KW[13] = {0,1,2,3,4,0,1,2,3,4,0,1,2};

    f32x16 acc[2][2];
    #pragma unroll
    for (int pt = 0; pt < 2; ++pt)
        #pragma unroll
        for (int ot = 0; ot < 2; ++ot)
            #pragma unroll
            for (int r = 0; r < 16; ++r) acc[pt][ot][r] = 0.f;

    const unsigned short* gbase_n = in + (size_t)n * NKC * ICS16;

    // prologue: stage ic=0 into buf 0
    #pragma unroll
    for (int it = 0; it < 5; ++it)
        __builtin_amdgcn_global_load_lds((gas_t)(gbase_n + goff[it]),
                                         (las_t)&Xs[0][(wv * 5 + it) * 512], 16, 0, 0);
    __syncthreads();

#define LOAD_XA(dst, u) do {                                              \
        int t_ = (u) >> 1, hf_ = (u) & 1;                                 \
        int so_ = hf_ * HFSH + (wr + KH[t_]) * (TC * 16)                  \
                + (lo5 + KW[t_]) * 16 + hi * 8;                           \
        (dst)[0] = *(const short8*)&xs[so_];                              \
        (dst)[1] = *(const short8*)&xs[so_ + 512];                        \
    } while (0)

#define LOAD_WB(dst, u) do {                                              \
        int t_ = (u) >> 1, hf_ = (u) & 1;                                 \
        const unsigned short* wb_ = wp +                                  \
            (size_t)((t_ * NKC + ic * 2 + hf_) * C_CH + o0 + wc * 64) * 16; \
        (dst)[0] = *(const short8*)&wb_[lo5 * 16 + hi * 8];               \
        (dst)[1] = *(const short8*)&wb_[(32 + lo5) * 16 + hi * 8];        \
    } while (0)

    for (int ic = 0; ic < 12; ++ic) {
        int buf = ic & 1;
        const unsigned short* xs = &Xs[buf][0];
        short8 xa[2][2];
        short8 wb[3][2];
        // wb first: their vmcnt position precedes the HBM stage loads
        LOAD_WB(wb[0], 0);
        LOAD_WB(wb[1], 1);
        // stage next ic into other buffer
        if (ic < 11) {
            const unsigned short* gb = gbase_n + (size_t)(ic + 1) * 2 * ICS16;
            #pragma unroll
            for (int it = 0; it < 5; ++it)
                __builtin_amdgcn_global_load_lds((gas_t)(gb + goff[it]),
                                                 (las_t)&Xs[buf ^ 1][(wv * 5 + it) * 512], 16, 0, 0);
        }
        LOAD_XA(xa[0], 0);

        #pragma unroll
        for (int s2 = 0; s2 < 26; ++s2) {
            if (s2 + 2 < 26) LOAD_WB(wb[(s2 + 2) % 3], s2 + 2);
            if (s2 + 1 < 26) LOAD_XA(xa[(s2 + 1) & 1], s2 + 1);
            __builtin_amdgcn_s_setprio(1);
            #pragma unroll
            for (int pt = 0; pt < 2; ++pt)
                #pragma unroll
                for (int ot = 0; ot < 2; ++ot) {
                    if (SECOND)
                        acc[pt][ot] = __builtin_amdgcn_mfma_f32_32x32x16_bf16(
                            wb[s2 % 3][ot], xa[s2 & 1][pt], acc[pt][ot], 0, 0, 0);
                    else
                        acc[pt][ot] = __builtin_amdgcn_mfma_f32_32x32x16_bf16(
                            xa[s2 & 1][pt], wb[s2 % 3][ot], acc[pt][ot], 0, 0, 0);
                }
            __builtin_amdgcn_s_setprio(0);
        }
        __syncthreads();
    }
#undef LOAD_XA
#undef LOAD_WB

    int h = h0 + wr;
    if (!SECOND) {
        // D[p][o]: p = pt*32 + (reg&3)+8*(reg>>2)+4*hi ; o = o0+wc*64+ot*32+lo5
        unsigned short* y = (unsigned short*)outp;
        #pragma unroll
        for (int ot = 0; ot < 2; ++ot) {
            int o = o0 + wc * 64 + ot * 32 + lo5;
            float bo = bias[o], ao = alpha[o];
            int kc = o >> 4;
            int o15 = o & 15;
            size_t base = (size_t)(n * NKC + kc) * ICS16 + ((h + 2) * PC + (w0 + 2)) * 16 + o15;
            #pragma unroll
            for (int pt = 0; pt < 2; ++pt) {
                #pragma unroll
                for (int reg = 0; reg < 16; ++reg) {
                    int p = pt * 32 + (reg & 3) + 8 * (reg >> 2) + 4 * hi;
                    float v = acc[pt][ot][reg] + bo;
                    v = v >= 0.f ? v : ao * v;
                    y[base + (size_t)p * 16] = f2bf(v);
                }
            }
        }
    } else {
        // D[o][p]: o = o0+wc*64+ot*32+(reg&3)+8*(reg>>2)+4*hi ; w = w0+pt*32+lo5
        float* outf = (float*)outp;
        #pragma unroll
        for (int ot = 0; ot < 2; ++ot) {
            #pragma unroll
            for (int reg = 0; reg < 16; ++reg) {
                int o = o0 + wc * 64 + ot * 32 + (reg & 3) + 8 * (reg >> 2) + 4 * hi;
                float bo = bias[o], ao = alpha[o];
                #pragma unroll
                for (int pt = 0; pt < 2; ++pt) {
                    int w = w0 + pt * 32 + lo5;
                    float v = acc[pt][ot][reg] + bo;
                    v = v >= 0.f ? v : ao * v;
                    size_t idx = (size_t)((n * C_CH + o) * HH + h) * WWD + w;
                    outf[idx] = v + xres[idx];
                }
            }
        }
    }
}

extern "C" void kernel_launch(void* const* d_in, const int* in_sizes, int n_in,
                              void* d_out, int out_size, void* d_ws, size_t ws_size,
                              hipStream_t stream) {
    const float* x  = (const float*)d_in[0];
    const float* w1 = (const float*)d_in[1];
    const float* b1 = (const float*)d_in[2];
    const float* a1 = (const float*)d_in[3];
    const float* w2 = (const float*)d_in[4];
    const float* b2 = (const float*)d_in[5];
    const float* a2 = (const float*)d_in[6];

    const size_t PLANE_SHORTS = (size_t)NN * NKC * ICS16;       // 103,034,880 shorts
    unsigned short* xc  = (unsigned short*)d_out;               // 206,069,760 B scratch in d_out
    unsigned short* yb  = (unsigned short*)d_ws;                // 206,069,760 B
    unsigned short* wp1 = yb + PLANE_SHORTS;                    // 3,833,856 B
    unsigned short* wp2 = wp1 + 13 * NKC * C_CH * 16;           // 3,833,856 B

    k_prepack<<<(13 * NKC * C_CH * 16 + 255) / 256, 256, 0, stream>>>(w1, w2, wp1, wp2);
    k_zero_halo<<<NN * NKC, 256, 0, stream>>>(xc, yb);
    k_repack_x<<<NN * HH * (WWD / 64), 256, 0, stream>>>(x, xc);
    k_conv<0><<<6144, 256, 0, stream>>>(xc, wp1, b1, a1, nullptr, (void*)yb);
    k_conv<1><<<6144, 256, 0, stream>>>(yb, wp2, b2, a2, x, (void*)d_out);
}

// Round 6
// 1876.824 us; speedup vs baseline: 1.1218x; 1.1218x over previous
//
#include <hip/hip_runtime.h>
#include <hip/hip_bf16.h>

// EntropyResidualBlock: y1 = prelu(maskconv(x,w1)+b1); y2 = prelu(maskconv(y1,w2)+b2); out = y2 + x
// 13 live taps. Implicit GEMM with mfma_f32_32x32x16_bf16.
//   conv1: D[p][o] = sum X[p+d(t)][i]*W1[t][i][o]  (A=X,B=W);  conv2: D[o][p] (A=W,B=Y).
// Layouts: X/Y packed [n][kc=24 x 16ch][h+4][w+4][16] bf16 (halo-padded);
//          W packed [t][kc][o][16] bf16 (masked).
// Round-6: R4 geometry (2h x 128w x 128o block, 4 waves, per-wave 128p x 64o,
// acc 4x2 f32x16) + vmcnt-queue discipline: wb ring-2 CONTINUOUS across ic
// boundaries (next-ic wb u=0,1 prefetched at steps 24,25, BEFORE the next stage
// block) so wb L2 loads are never trapped behind the 900-cyc HBM staging drain.
// Consume-then-prefetch ring order; xa 1-ahead (2 sets); setprio around MFMA.
// Halo-zero kernel instead of 412MB memsets. Xc in d_out; ws: [Y][Wp1][Wp2].

#define C_CH 384
#define HH   256
#define WWD  512
#define NN   2
#define NKC  24                    // 16-channel chunks
#define PR   260
#define PC   516
#define ICS16 (PR * PC * 16)       // shorts per (n,kc) plane = 2,146,560
#define TCOLS 144
#define PLANE_SH (4 * TCOLS * 16)  // 9216 shorts per hf sub-plane in LDS
#define TSH (2 * PLANE_SH)         // 18432 shorts = 36,864 B per buffer

typedef __attribute__((ext_vector_type(8)))  short short8;
typedef __attribute__((ext_vector_type(16))) float f32x16;

typedef const __attribute__((address_space(1))) void* gas_t;
typedef __attribute__((address_space(3))) void* las_t;

__device__ inline unsigned short f2bf(float f) {
    union { float f; unsigned int u; } v; v.f = f;
    unsigned int r = v.u + 0x7FFFu + ((v.u >> 16) & 1u);
    return (unsigned short)(r >> 16);
}

// ---------------- weights -> bf16 wp[t][kc][o][16], masked ----------------
__global__ __launch_bounds__(256) void k_prepack(const float* __restrict__ w1, const float* __restrict__ w2,
                                                 unsigned short* __restrict__ wp1, unsigned short* __restrict__ wp2) {
    int idx = blockIdx.x * 256 + threadIdx.x;
    const int TOT = 13 * NKC * C_CH * 16;
    if (idx >= TOT) return;
    int iq = idx & 15;
    int o  = (idx >> 4) % C_CH;
    int kc = (idx / (16 * C_CH)) % NKC;
    int t  = idx / (16 * C_CH * NKC);
    int i  = kc * 16 + iq;
    int kh = t < 5 ? 0 : (t < 10 ? 1 : 2);
    int kw = t < 5 ? t : (t < 10 ? t - 5 : t - 10);
    bool keep = (t != 12) || ((i / 24) <= (o / 24));
    int src = ((o * C_CH + i) * 5 + kh) * 5 + kw;
    wp1[idx] = keep ? f2bf(w1[src]) : (unsigned short)0;
    wp2[idx] = keep ? f2bf(w2[src]) : (unsigned short)0;
}

// ---------------- zero the halo borders of both packed buffers ----------------
__global__ __launch_bounds__(256) void k_zero_halo(unsigned short* __restrict__ a, unsigned short* __restrict__ b) {
    int plane = blockIdx.x;            // 0..47 (n*NKC+kc)
    const short8 z = (short8){0,0,0,0,0,0,0,0};
    for (int bi = 0; bi < 2; ++bi) {
        unsigned short* p = (bi ? b : a) + (size_t)plane * ICS16;
        // top rows 0,1 + bottom rows 258,259: 4 rows x 516 cols x 2 q = 4128 short8
        for (int i = threadIdx.x; i < 4128; i += 256) {
            int r4 = i / 1032;
            int rem = i - r4 * 1032;
            int row = r4 < 2 ? r4 : 254 + r4;
            *(short8*)&p[row * (PC * 16) + rem * 8] = z;
        }
        // side cols 0,1,514,515 for rows 2..257: 256 rows x 8 short8
        for (int i = threadIdx.x; i < 2048; i += 256) {
            int row = 2 + (i >> 3);
            int j = i & 7;
            int col = (j < 4) ? (j >> 1) : (512 + (j >> 1));
            int q = j & 1;
            *(short8*)&p[(row * PC + col) * 16 + q * 8] = z;
        }
    }
}

// ---------------- x NCHW fp32 -> padded 16ch-chunked bf16 ----------------
__global__ __launch_bounds__(256) void k_repack_x(const float* __restrict__ x, unsigned short* __restrict__ xc) {
    int bid = blockIdx.x;              // 4096 blocks: 64 w x 384 c for one (n,h)
    int w0 = (bid & 7) << 6;
    int h  = (bid >> 3) & 255;
    int n  = bid >> 11;
    int wi = threadIdx.x & 63;
    int cq = threadIdx.x >> 6;         // 0..3 (8 channels each)
    int w  = w0 + wi;
    int inb = n * C_CH * HH * WWD + h * WWD + w;
    for (int cc = 0; cc < 12; ++cc) {
        int c0 = cc * 32 + cq * 8;
        short8 outv;
        #pragma unroll
        for (int k = 0; k < 8; ++k) {
            float f = x[inb + (c0 + k) * (HH * WWD)];
            outv[k] = (short)f2bf(f);
        }
        int kc = cc * 2 + (cq >> 1);
        int oidx = (n * NKC + kc) * ICS16 + ((h + 2) * PC + (w + 2)) * 16 + (cq & 1) * 8;
        *(short8*)&xc[oidx] = outv;
    }
}

// ---------------- masked conv via 32x32x16 MFMA ----------------
// grid 3072; 256 threads / 4 waves (wr = h-row 0/1, wc = o-half).
template<int SECOND>
__global__ __launch_bounds__(256, 2) void k_conv(const unsigned short* __restrict__ in,   // packed
                                                 const unsigned short* __restrict__ wp,
                                                 const float* __restrict__ bias,
                                                 const float* __restrict__ alpha,
                                                 const float* __restrict__ xres,
                                                 void* __restrict__ outp) {
    __shared__ __align__(16) unsigned short Xs[2][TSH];   // 2 x 36,864 B

    // ob slow within XCD chunk: 3 ob-blocks of one tile run consecutively on one XCD
    int bid0 = blockIdx.x;
    int xcd = bid0 & 7;
    int j0  = bid0 >> 3;
    int tile = xcd * 128 + j0 / 3;
    int ob   = j0 % 3;
    int n    = tile >> 9;
    int hp   = (tile >> 2) & 127;
    int wseg = tile & 3;
    int w0 = wseg << 7, o0 = ob << 7, h0 = hp << 1;

    int tid = threadIdx.x;
    int lane = tid & 63;
    int wv = tid >> 6;
    int wr = wv >> 1, wc = wv & 1;
    int lo5 = lane & 31, hi = lane >> 5;

    // staging: 36 wave-issues per buffer, 9 per wave; per-lane global offsets
    int goff[9];
    #pragma unroll
    for (int it = 0; it < 9; ++it) {
        int k = wv * 9 + it;
        int plane = k / 18;
        int s = (k % 18) * 64 + lane;
        int r = s / 288;
        int rem = s - r * 288;
        int col = rem >> 1, h16 = rem & 1;
        goff[it] = plane * ICS16 + ((h0 + r) * PC + (w0 + col)) * 16 + h16 * 8;
    }

    const int KH[13] = {0,0,0,0,0,1,1,1,1,1,2,2,2};
    const int KW[13] = {0,1,2,3,4,0,1,2,3,4,0,1,2};

    f32x16 acc[4][2];
    #pragma unroll
    for (int pt = 0; pt < 4; ++pt)
        #pragma unroll
        for (int ot = 0; ot < 2; ++ot)
            #pragma unroll
            for (int r = 0; r < 16; ++r) acc[pt][ot][r] = 0.f;

    const unsigned short* gbase_n = in + (size_t)n * NKC * ICS16;

#define LOAD_XA(dst, u) do {                                              \
        int t_ = (u) >> 1, hf_ = (u) & 1;                                 \
        int so_ = hf_ * PLANE_SH + (wr + KH[t_]) * (TCOLS * 16)           \
                + (lo5 + KW[t_]) * 16 + hi * 8;                           \
        _Pragma("unroll")                                                 \
        for (int pt_ = 0; pt_ < 4; ++pt_)                                 \
            (dst)[pt_] = *(const short8*)&xs[so_ + pt_ * 512];            \
    } while (0)

#define LOAD_WB(dst, icc, u) do {                                         \
        int t_ = (u) >> 1, hf_ = (u) & 1;                                 \
        const unsigned short* wb_ = wp +                                  \
            (size_t)((t_ * NKC + (icc) * 2 + hf_) * C_CH + o0 + wc * 64) * 16; \
        _Pragma("unroll")                                                 \
        for (int ot_ = 0; ot_ < 2; ++ot_)                                 \
            (dst)[ot_] = *(const short8*)&wb_[(ot_ * 32 + lo5) * 16 + hi * 8]; \
    } while (0)

    short8 wb[2][2];
    // wb for (ic=0, u=0,1) issued FIRST: ahead of all staging in the vmcnt queue
    LOAD_WB(wb[0], 0, 0);
    LOAD_WB(wb[1], 0, 1);

    // prologue: stage ic=0 into buf 0
    #pragma unroll
    for (int it = 0; it < 9; ++it)
        __builtin_amdgcn_global_load_lds((gas_t)(gbase_n + goff[it]),
                                         (las_t)&Xs[0][(wv * 9 + it) * 512], 16, 0, 0);
    __syncthreads();

    for (int ic = 0; ic < 12; ++ic) {
        int buf = ic & 1;
        const unsigned short* xs = &Xs[buf][0];
        // stage next ic into other buffer (wb for steps 0,1 already issued earlier)
        if (ic < 11) {
            const unsigned short* gb = gbase_n + (size_t)(ic + 1) * 2 * ICS16;
            #pragma unroll
            for (int it = 0; it < 9; ++it)
                __builtin_amdgcn_global_load_lds((gas_t)(gb + goff[it]),
                                                 (las_t)&Xs[buf ^ 1][(wv * 9 + it) * 512], 16, 0, 0);
        }

        short8 xa[2][4];
        LOAD_XA(xa[0], 0);
        int icn = ic < 11 ? ic + 1 : 11;   // cross-ic wb prefetch target

        #pragma unroll
        for (int s2 = 0; s2 < 26; ++s2) {
            if (s2 + 1 < 26) LOAD_XA(xa[(s2 + 1) & 1], s2 + 1);
            __builtin_amdgcn_s_setprio(1);
            #pragma unroll
            for (int pt = 0; pt < 4; ++pt)
                #pragma unroll
                for (int ot = 0; ot < 2; ++ot) {
                    if (SECOND)
                        acc[pt][ot] = __builtin_amdgcn_mfma_f32_32x32x16_bf16(
                            wb[s2 & 1][ot], xa[s2 & 1][pt], acc[pt][ot], 0, 0, 0);
                    else
                        acc[pt][ot] = __builtin_amdgcn_mfma_f32_32x32x16_bf16(
                            xa[s2 & 1][pt], wb[s2 & 1][ot], acc[pt][ot], 0, 0, 0);
                }
            __builtin_amdgcn_s_setprio(0);
            // consume-then-prefetch: refill the slot just used with u = s2+2
            // (steps 24,25 fetch NEXT ic's u=0,1 -> issued before next stage block)
            if (s2 + 2 < 26) {
                LOAD_WB(wb[s2 & 1], ic, s2 + 2);
            } else {
                LOAD_WB(wb[s2 & 1], icn, s2 - 24);
            }
        }
        __syncthreads();
    }
#undef LOAD_XA
#undef LOAD_WB

    int h = h0 + wr;
    if (!SECOND) {
        // D[p][o]: p = pt*32 + (reg&3)+8*(reg>>2)+4*hi ; o = o0+wc*64+ot*32+lo5
        unsigned short* y = (unsigned short*)outp;
        #pragma unroll
        for (int ot = 0; ot < 2; ++ot) {
            int o = o0 + wc * 64 + ot * 32 + lo5;
            float bo = bias[o], ao = alpha[o];
            int kc = o >> 4;
            int o15 = o & 15;
            size_t base = (size_t)(n * NKC + kc) * ICS16 + ((h + 2) * PC + (w0 + 2)) * 16 + o15;
            #pragma unroll
            for (int pt = 0; pt < 4; ++pt) {
                #pragma unroll
                for (int reg = 0; reg < 16; ++reg) {
                    int p = pt * 32 + (reg & 3) + 8 * (reg >> 2) + 4 * hi;
                    float v = acc[pt][ot][reg] + bo;
                    v = v >= 0.f ? v : ao * v;
                    y[base + (size_t)p * 16] = f2bf(v);
                }
            }
        }
    } else {
        // D[o][p]: o = o0+wc*64+ot*32+(reg&3)+8*(reg>>2)+4*hi ; w = w0+pt*32+lo5
        float* outf = (float*)outp;
        #pragma unroll
        for (int ot = 0; ot < 2; ++ot) {
            #pragma unroll
            for (int reg = 0; reg < 16; ++reg) {
                int o = o0 + wc * 64 + ot * 32 + (reg & 3) + 8 * (reg >> 2) + 4 * hi;
                float bo = bias[o], ao = alpha[o];
                #pragma unroll
                for (int pt = 0; pt < 4; ++pt) {
                    int w = w0 + pt * 32 + lo5;
                    float v = acc[pt][ot][reg] + bo;
                    v = v >= 0.f ? v : ao * v;
                    size_t idx = (size_t)((n * C_CH + o) * HH + h) * WWD + w;
                    outf[idx] = v + xres[idx];
                }
            }
        }
    }
}

extern "C" void kernel_launch(void* const* d_in, const int* in_sizes, int n_in,
                              void* d_out, int out_size, void* d_ws, size_t ws_size,
                              hipStream_t stream) {
    const float* x  = (const float*)d_in[0];
    const float* w1 = (const float*)d_in[1];
    const float* b1 = (const float*)d_in[2];
    const float* a1 = (const float*)d_in[3];
    const float* w2 = (const float*)d_in[4];
    const float* b2 = (const float*)d_in[5];
    const float* a2 = (const float*)d_in[6];

    const size_t PLANE_SHORTS = (size_t)NN * NKC * ICS16;       // 103,034,880 shorts
    unsigned short* xc  = (unsigned short*)d_out;               // 206,069,760 B scratch in d_out
    unsigned short* yb  = (unsigned short*)d_ws;                // 206,069,760 B
    unsigned short* wp1 = yb + PLANE_SHORTS;                    // 3,833,856 B
    unsigned short* wp2 = wp1 + 13 * NKC * C_CH * 16;           // 3,833,856 B

    k_prepack<<<(13 * NKC * C_CH * 16 + 255) / 256, 256, 0, stream>>>(w1, w2, wp1, wp2);
    k_zero_halo<<<NN * NKC, 256, 0, stream>>>(xc, yb);
    k_repack_x<<<NN * HH * (WWD / 64), 256, 0, stream>>>(x, xc);
    k_conv<0><<<3072, 256, 0, stream>>>(xc, wp1, b1, a1, nullptr, (void*)yb);
    k_conv<1><<<3072, 256, 0, stream>>>(yb, wp2, b2, a2, x, (void*)d_out);
}

// Round 7
// 1858.632 us; speedup vs baseline: 1.1328x; 1.0098x over previous
//
#include <hip/hip_runtime.h>
#include <hip/hip_bf16.h>

// EntropyResidualBlock: y1 = prelu(maskconv(x,w1)+b1); y2 = prelu(maskconv(y1,w2)+b2); out = y2 + x
// 13 live taps. Implicit GEMM with mfma_f32_32x32x16_bf16.
//   conv1: D[p][o] = sum X[p+d(t)][i]*W1[t][i][o]  (A=X,B=W);  conv2: D[o][p] (A=W,B=Y).
// Layouts: X/Y packed [n][kc=24 x 16ch][h+4][w+4][16] bf16 (halo-padded);
//          W packed [t][kc][o][16] bf16 (masked).
// Round-7: R6 + counted-vmcnt barrier (T4). The in-loop __syncthreads drained
// vmcnt(0) -> waited on just-issued wb L2 loads every ic. Replaced with
// "s_waitcnt vmcnt(52); s_barrier" in ONE asm volatile: per-wave issue order per ic
// is [9 staging][52 wb], so vmcnt(52) retires exactly the staging (in-order counter)
// and leaves wb prefetches in flight across the barrier. Prologue keeps full
// __syncthreads; trailing barrier dropped.
// wb ring-2 continuous across ic (next-ic u=0,1 at steps 24,25, before next stage
// block); xa 1-ahead; setprio around MFMA octet; halo-zero kernel; Xc in d_out.

#define C_CH 384
#define HH   256
#define WWD  512
#define NN   2
#define NKC  24                    // 16-channel chunks
#define PR   260
#define PC   516
#define ICS16 (PR * PC * 16)       // shorts per (n,kc) plane = 2,146,560
#define TCOLS 144
#define PLANE_SH (4 * TCOLS * 16)  // 9216 shorts per hf sub-plane in LDS
#define TSH (2 * PLANE_SH)         // 18432 shorts = 36,864 B per buffer

typedef __attribute__((ext_vector_type(8)))  short short8;
typedef __attribute__((ext_vector_type(16))) float f32x16;

typedef const __attribute__((address_space(1))) void* gas_t;
typedef __attribute__((address_space(3))) void* las_t;

__device__ inline unsigned short f2bf(float f) {
    union { float f; unsigned int u; } v; v.f = f;
    unsigned int r = v.u + 0x7FFFu + ((v.u >> 16) & 1u);
    return (unsigned short)(r >> 16);
}

// ---------------- weights -> bf16 wp[t][kc][o][16], masked ----------------
__global__ __launch_bounds__(256) void k_prepack(const float* __restrict__ w1, const float* __restrict__ w2,
                                                 unsigned short* __restrict__ wp1, unsigned short* __restrict__ wp2) {
    int idx = blockIdx.x * 256 + threadIdx.x;
    const int TOT = 13 * NKC * C_CH * 16;
    if (idx >= TOT) return;
    int iq = idx & 15;
    int o  = (idx >> 4) % C_CH;
    int kc = (idx / (16 * C_CH)) % NKC;
    int t  = idx / (16 * C_CH * NKC);
    int i  = kc * 16 + iq;
    int kh = t < 5 ? 0 : (t < 10 ? 1 : 2);
    int kw = t < 5 ? t : (t < 10 ? t - 5 : t - 10);
    bool keep = (t != 12) || ((i / 24) <= (o / 24));
    int src = ((o * C_CH + i) * 5 + kh) * 5 + kw;
    wp1[idx] = keep ? f2bf(w1[src]) : (unsigned short)0;
    wp2[idx] = keep ? f2bf(w2[src]) : (unsigned short)0;
}

// ---------------- zero the halo borders of both packed buffers ----------------
__global__ __launch_bounds__(256) void k_zero_halo(unsigned short* __restrict__ a, unsigned short* __restrict__ b) {
    int plane = blockIdx.x;            // 0..47 (n*NKC+kc)
    const short8 z = (short8){0,0,0,0,0,0,0,0};
    for (int bi = 0; bi < 2; ++bi) {
        unsigned short* p = (bi ? b : a) + (size_t)plane * ICS16;
        // top rows 0,1 + bottom rows 258,259: 4 rows x 516 cols x 2 q = 4128 short8
        for (int i = threadIdx.x; i < 4128; i += 256) {
            int r4 = i / 1032;
            int rem = i - r4 * 1032;
            int row = r4 < 2 ? r4 : 254 + r4;
            *(short8*)&p[row * (PC * 16) + rem * 8] = z;
        }
        // side cols 0,1,514,515 for rows 2..257: 256 rows x 8 short8
        for (int i = threadIdx.x; i < 2048; i += 256) {
            int row = 2 + (i >> 3);
            int j = i & 7;
            int col = (j < 4) ? (j >> 1) : (512 + (j >> 1));
            int q = j & 1;
            *(short8*)&p[(row * PC + col) * 16 + q * 8] = z;
        }
    }
}

// ---------------- x NCHW fp32 -> padded 16ch-chunked bf16 ----------------
__global__ __launch_bounds__(256) void k_repack_x(const float* __restrict__ x, unsigned short* __restrict__ xc) {
    int bid = blockIdx.x;              // 4096 blocks: 64 w x 384 c for one (n,h)
    int w0 = (bid & 7) << 6;
    int h  = (bid >> 3) & 255;
    int n  = bid >> 11;
    int wi = threadIdx.x & 63;
    int cq = threadIdx.x >> 6;         // 0..3 (8 channels each)
    int w  = w0 + wi;
    int inb = n * C_CH * HH * WWD + h * WWD + w;
    for (int cc = 0; cc < 12; ++cc) {
        int c0 = cc * 32 + cq * 8;
        short8 outv;
        #pragma unroll
        for (int k = 0; k < 8; ++k) {
            float f = x[inb + (c0 + k) * (HH * WWD)];
            outv[k] = (short)f2bf(f);
        }
        int kc = cc * 2 + (cq >> 1);
        int oidx = (n * NKC + kc) * ICS16 + ((h + 2) * PC + (w + 2)) * 16 + (cq & 1) * 8;
        *(short8*)&xc[oidx] = outv;
    }
}

// ---------------- masked conv via 32x32x16 MFMA ----------------
// grid 3072; 256 threads / 4 waves (wr = h-row 0/1, wc = o-half).
template<int SECOND>
__global__ __launch_bounds__(256, 2) void k_conv(const unsigned short* __restrict__ in,   // packed
                                                 const unsigned short* __restrict__ wp,
                                                 const float* __restrict__ bias,
                                                 const float* __restrict__ alpha,
                                                 const float* __restrict__ xres,
                                                 void* __restrict__ outp) {
    __shared__ __align__(16) unsigned short Xs[2][TSH];   // 2 x 36,864 B

    // ob slow within XCD chunk: 3 ob-blocks of one tile run consecutively on one XCD
    int bid0 = blockIdx.x;
    int xcd = bid0 & 7;
    int j0  = bid0 >> 3;
    int tile = xcd * 128 + j0 / 3;
    int ob   = j0 % 3;
    int n    = tile >> 9;
    int hp   = (tile >> 2) & 127;
    int wseg = tile & 3;
    int w0 = wseg << 7, o0 = ob << 7, h0 = hp << 1;

    int tid = threadIdx.x;
    int lane = tid & 63;
    int wv = tid >> 6;
    int wr = wv >> 1, wc = wv & 1;
    int lo5 = lane & 31, hi = lane >> 5;

    // staging: 36 wave-issues per buffer, 9 per wave; per-lane global offsets
    int goff[9];
    #pragma unroll
    for (int it = 0; it < 9; ++it) {
        int k = wv * 9 + it;
        int plane = k / 18;
        int s = (k % 18) * 64 + lane;
        int r = s / 288;
        int rem = s - r * 288;
        int col = rem >> 1, h16 = rem & 1;
        goff[it] = plane * ICS16 + ((h0 + r) * PC + (w0 + col)) * 16 + h16 * 8;
    }

    const int KH[13] = {0,0,0,0,0,1,1,1,1,1,2,2,2};
    const int KW[13] = {0,1,2,3,4,0,1,2,3,4,0,1,2};

    f32x16 acc[4][2];
    #pragma unroll
    for (int pt = 0; pt < 4; ++pt)
        #pragma unroll
        for (int ot = 0; ot < 2; ++ot)
            #pragma unroll
            for (int r = 0; r < 16; ++r) acc[pt][ot][r] = 0.f;

    const unsigned short* gbase_n = in + (size_t)n * NKC * ICS16;

#define LOAD_XA(dst, u) do {                                              \
        int t_ = (u) >> 1, hf_ = (u) & 1;                                 \
        int so_ = hf_ * PLANE_SH + (wr + KH[t_]) * (TCOLS * 16)           \
                + (lo5 + KW[t_]) * 16 + hi * 8;                           \
        _Pragma("unroll")                                                 \
        for (int pt_ = 0; pt_ < 4; ++pt_)                                 \
            (dst)[pt_] = *(const short8*)&xs[so_ + pt_ * 512];            \
    } while (0)

#define LOAD_WB(dst, icc, u) do {                                         \
        int t_ = (u) >> 1, hf_ = (u) & 1;                                 \
        const unsigned short* wb_ = wp +                                  \
            (size_t)((t_ * NKC + (icc) * 2 + hf_) * C_CH + o0 + wc * 64) * 16; \
        _Pragma("unroll")                                                 \
        for (int ot_ = 0; ot_ < 2; ++ot_)                                 \
            (dst)[ot_] = *(const short8*)&wb_[(ot_ * 32 + lo5) * 16 + hi * 8]; \
    } while (0)

    short8 wb[2][2];
    // wb for (ic=0, u=0,1) issued FIRST: ahead of all staging in the vmcnt queue
    LOAD_WB(wb[0], 0, 0);
    LOAD_WB(wb[1], 0, 1);

    // prologue: stage ic=0 into buf 0
    #pragma unroll
    for (int it = 0; it < 9; ++it)
        __builtin_amdgcn_global_load_lds((gas_t)(gbase_n + goff[it]),
                                         (las_t)&Xs[0][(wv * 9 + it) * 512], 16, 0, 0);
    __syncthreads();

    for (int ic = 0; ic < 12; ++ic) {
        int buf = ic & 1;
        const unsigned short* xs = &Xs[buf][0];
        // stage next ic into other buffer (wb for steps 0,1 already issued earlier)
        if (ic < 11) {
            const unsigned short* gb = gbase_n + (size_t)(ic + 1) * 2 * ICS16;
            #pragma unroll
            for (int it = 0; it < 9; ++it)
                __builtin_amdgcn_global_load_lds((gas_t)(gb + goff[it]),
                                                 (las_t)&Xs[buf ^ 1][(wv * 9 + it) * 512], 16, 0, 0);
        }

        short8 xa[2][4];
        LOAD_XA(xa[0], 0);
        int icn = ic < 11 ? ic + 1 : 11;   // cross-ic wb prefetch target

        #pragma unroll
        for (int s2 = 0; s2 < 26; ++s2) {
            if (s2 + 1 < 26) LOAD_XA(xa[(s2 + 1) & 1], s2 + 1);
            __builtin_amdgcn_s_setprio(1);
            #pragma unroll
            for (int pt = 0; pt < 4; ++pt)
                #pragma unroll
                for (int ot = 0; ot < 2; ++ot) {
                    if (SECOND)
                        acc[pt][ot] = __builtin_amdgcn_mfma_f32_32x32x16_bf16(
                            wb[s2 & 1][ot], xa[s2 & 1][pt], acc[pt][ot], 0, 0, 0);
                    else
                        acc[pt][ot] = __builtin_amdgcn_mfma_f32_32x32x16_bf16(
                            xa[s2 & 1][pt], wb[s2 & 1][ot], acc[pt][ot], 0, 0, 0);
                }
            __builtin_amdgcn_s_setprio(0);
            // consume-then-prefetch: refill the slot just used with u = s2+2
            // (steps 24,25 fetch NEXT ic's u=0,1 -> issued before next stage block)
            if (s2 + 2 < 26) {
                LOAD_WB(wb[s2 & 1], ic, s2 + 2);
            } else {
                LOAD_WB(wb[s2 & 1], icn, s2 - 24);
            }
        }
        // Counted-vmcnt barrier (T4): per-wave issue order this ic was
        // [9 staging][52 wb], so vmcnt(52) retires exactly the staging (in-order
        // counter retirement) while leaving the wb prefetches in flight.
        // Single asm block: nothing can be scheduled between wait and barrier,
        // and no memory op can cross it.
        if (ic < 11)
            asm volatile("s_waitcnt vmcnt(52)\n\ts_barrier" ::: "memory");
    }
#undef LOAD_XA
#undef LOAD_WB

    int h = h0 + wr;
    if (!SECOND) {
        // D[p][o]: p = pt*32 + (reg&3)+8*(reg>>2)+4*hi ; o = o0+wc*64+ot*32+lo5
        unsigned short* y = (unsigned short*)outp;
        #pragma unroll
        for (int ot = 0; ot < 2; ++ot) {
            int o = o0 + wc * 64 + ot * 32 + lo5;
            float bo = bias[o], ao = alpha[o];
            int kc = o >> 4;
            int o15 = o & 15;
            size_t base = (size_t)(n * NKC + kc) * ICS16 + ((h + 2) * PC + (w0 + 2)) * 16 + o15;
            #pragma unroll
            for (int pt = 0; pt < 4; ++pt) {
                #pragma unroll
                for (int reg = 0; reg < 16; ++reg) {
                    int p = pt * 32 + (reg & 3) + 8 * (reg >> 2) + 4 * hi;
                    float v = acc[pt][ot][reg] + bo;
                    v = v >= 0.f ? v : ao * v;
                    y[base + (size_t)p * 16] = f2bf(v);
                }
            }
        }
    } else {
        // D[o][p]: o = o0+wc*64+ot*32+(reg&3)+8*(reg>>2)+4*hi ; w = w0+pt*32+lo5
        float* outf = (float*)outp;
        #pragma unroll
        for (int ot = 0; ot < 2; ++ot) {
            #pragma unroll
            for (int reg = 0; reg < 16; ++reg) {
                int o = o0 + wc * 64 + ot * 32 + (reg & 3) + 8 * (reg >> 2) + 4 * hi;
                float bo = bias[o], ao = alpha[o];
                #pragma unroll
                for (int pt = 0; pt < 4; ++pt) {
                    int w = w0 + pt * 32 + lo5;
                    float v = acc[pt][ot][reg] + bo;
                    v = v >= 0.f ? v : ao * v;
                    size_t idx = (size_t)((n * C_CH + o) * HH + h) * WWD + w;
                    outf[idx] = v + xres[idx];
                }
            }
        }
    }
}

extern "C" void kernel_launch(void* const* d_in, const int* in_sizes, int n_in,
                              void* d_out, int out_size, void* d_ws, size_t ws_size,
                              hipStream_t stream) {
    const float* x  = (const float*)d_in[0];
    const float* w1 = (const float*)d_in[1];
    const float* b1 = (const float*)d_in[2];
    const float* a1 = (const float*)d_in[3];
    const float* w2 = (const float*)d_in[4];
    const float* b2 = (const float*)d_in[5];
    const float* a2 = (const float*)d_in[6];

    const size_t PLANE_SHORTS = (size_t)NN * NKC * ICS16;       // 103,034,880 shorts
    unsigned short* xc  = (unsigned short*)d_out;               // 206,069,760 B scratch in d_out
    unsigned short* yb  = (unsigned short*)d_ws;                // 206,069,760 B
    unsigned short* wp1 = yb + PLANE_SHORTS;                    // 3,833,856 B
    unsigned short* wp2 = wp1 + 13 * NKC * C_CH * 16;           // 3,833,856 B

    k_prepack<<<(13 * NKC * C_CH * 16 + 255) / 256, 256, 0, stream>>>(w1, w2, wp1, wp2);
    k_zero_halo<<<NN * NKC, 256, 0, stream>>>(xc, yb);
    k_repack_x<<<NN * HH * (WWD / 64), 256, 0, stream>>>(x, xc);
    k_conv<0><<<3072, 256, 0, stream>>>(xc, wp1, b1, a1, nullptr, (void*)yb);
    k_conv<1><<<3072, 256, 0, stream>>>(yb, wp2, b2, a2, x, (void*)d_out);
}

// Round 9
// 1808.224 us; speedup vs baseline: 1.1643x; 1.0279x over previous
//
#include <hip/hip_runtime.h>
#include <hip/hip_bf16.h>

// EntropyResidualBlock: y1 = prelu(maskconv(x,w1)+b1); y2 = prelu(maskconv(y1,w2)+b2); out = y2 + x
// 13 live taps. Implicit GEMM with mfma_f32_32x32x16_bf16.
//   conv1: D[p][o] = sum X[p+d(t)][i]*W1[t][i][o]  (A=X,B=W);  conv2: D[o][p] (A=W,B=Y).
// Layouts: X/Y packed [n][kc=24 x 16ch][h+4][w+4][16] bf16 (halo-padded);
//          W packed [t][kc][o][16] bf16 (masked).
// Round-9: exact R6 body (verified correct, 1877us) + per-step schedule-shaping
// s_barrier before each MFMA octet. Within an ic the LDS buffers are read-only
// (staging targets the other buffer), so these barriers guard nothing -> zero
// correctness risk; they exist to cluster each block's ds_reads and MFMAs so the
// 2 co-resident blocks anti-phase (block A's MFMA hides block B's LDS reads)
// instead of convoying. ic boundary keeps full __syncthreads (verified safe).
// wb ring-2 continuous across ic; xa 1-ahead; setprio around MFMA octet;
// halo-zero kernel; Xc in d_out (dead before conv2 writes d_out).

#define C_CH 384
#define HH   256
#define WWD  512
#define NN   2
#define NKC  24                    // 16-channel chunks
#define PR   260
#define PC   516
#define ICS16 (PR * PC * 16)       // shorts per (n,kc) plane = 2,146,560
#define TCOLS 144
#define PLANE_SH (4 * TCOLS * 16)  // 9216 shorts per hf sub-plane in LDS
#define TSH (2 * PLANE_SH)         // 18432 shorts = 36,864 B per buffer

typedef __attribute__((ext_vector_type(8)))  short short8;
typedef __attribute__((ext_vector_type(16))) float f32x16;

typedef const __attribute__((address_space(1))) void* gas_t;
typedef __attribute__((address_space(3))) void* las_t;

__device__ inline unsigned short f2bf(float f) {
    union { float f; unsigned int u; } v; v.f = f;
    unsigned int r = v.u + 0x7FFFu + ((v.u >> 16) & 1u);
    return (unsigned short)(r >> 16);
}

// ---------------- weights -> bf16 wp[t][kc][o][16], masked ----------------
__global__ __launch_bounds__(256) void k_prepack(const float* __restrict__ w1, const float* __restrict__ w2,
                                                 unsigned short* __restrict__ wp1, unsigned short* __restrict__ wp2) {
    int idx = blockIdx.x * 256 + threadIdx.x;
    const int TOT = 13 * NKC * C_CH * 16;
    if (idx >= TOT) return;
    int iq = idx & 15;
    int o  = (idx >> 4) % C_CH;
    int kc = (idx / (16 * C_CH)) % NKC;
    int t  = idx / (16 * C_CH * NKC);
    int i  = kc * 16 + iq;
    int kh = t < 5 ? 0 : (t < 10 ? 1 : 2);
    int kw = t < 5 ? t : (t < 10 ? t - 5 : t - 10);
    bool keep = (t != 12) || ((i / 24) <= (o / 24));
    int src = ((o * C_CH + i) * 5 + kh) * 5 + kw;
    wp1[idx] = keep ? f2bf(w1[src]) : (unsigned short)0;
    wp2[idx] = keep ? f2bf(w2[src]) : (unsigned short)0;
}

// ---------------- zero the halo borders of both packed buffers ----------------
__global__ __launch_bounds__(256) void k_zero_halo(unsigned short* __restrict__ a, unsigned short* __restrict__ b) {
    int plane = blockIdx.x;            // 0..47 (n*NKC+kc)
    const short8 z = (short8){0,0,0,0,0,0,0,0};
    for (int bi = 0; bi < 2; ++bi) {
        unsigned short* p = (bi ? b : a) + (size_t)plane * ICS16;
        // top rows 0,1 + bottom rows 258,259: 4 rows x 516 cols x 2 q = 4128 short8
        for (int i = threadIdx.x; i < 4128; i += 256) {
            int r4 = i / 1032;
            int rem = i - r4 * 1032;
            int row = r4 < 2 ? r4 : 254 + r4;
            *(short8*)&p[row * (PC * 16) + rem * 8] = z;
        }
        // side cols 0,1,514,515 for rows 2..257: 256 rows x 8 short8
        for (int i = threadIdx.x; i < 2048; i += 256) {
            int row = 2 + (i >> 3);
            int j = i & 7;
            int col = (j < 4) ? (j >> 1) : (512 + (j >> 1));
            int q = j & 1;
            *(short8*)&p[(row * PC + col) * 16 + q * 8] = z;
        }
    }
}

// ---------------- x NCHW fp32 -> padded 16ch-chunked bf16 ----------------
__global__ __launch_bounds__(256) void k_repack_x(const float* __restrict__ x, unsigned short* __restrict__ xc) {
    int bid = blockIdx.x;              // 4096 blocks: 64 w x 384 c for one (n,h)
    int w0 = (bid & 7) << 6;
    int h  = (bid >> 3) & 255;
    int n  = bid >> 11;
    int wi = threadIdx.x & 63;
    int cq = threadIdx.x >> 6;         // 0..3 (8 channels each)
    int w  = w0 + wi;
    int inb = n * C_CH * HH * WWD + h * WWD + w;
    for (int cc = 0; cc < 12; ++cc) {
        int c0 = cc * 32 + cq * 8;
        short8 outv;
        #pragma unroll
        for (int k = 0; k < 8; ++k) {
            float f = x[inb + (c0 + k) * (HH * WWD)];
            outv[k] = (short)f2bf(f);
        }
        int kc = cc * 2 + (cq >> 1);
        int oidx = (n * NKC + kc) * ICS16 + ((h + 2) * PC + (w + 2)) * 16 + (cq & 1) * 8;
        *(short8*)&xc[oidx] = outv;
    }
}

// ---------------- masked conv via 32x32x16 MFMA ----------------
// grid 3072; 256 threads / 4 waves (wr = h-row 0/1, wc = o-half).
template<int SECOND>
__global__ __launch_bounds__(256, 2) void k_conv(const unsigned short* __restrict__ in,   // packed
                                                 const unsigned short* __restrict__ wp,
                                                 const float* __restrict__ bias,
                                                 const float* __restrict__ alpha,
                                                 const float* __restrict__ xres,
                                                 void* __restrict__ outp) {
    __shared__ __align__(16) unsigned short Xs[2][TSH];   // 2 x 36,864 B

    // ob slow within XCD chunk: 3 ob-blocks of one tile run consecutively on one XCD
    int bid0 = blockIdx.x;
    int xcd = bid0 & 7;
    int j0  = bid0 >> 3;
    int tile = xcd * 128 + j0 / 3;
    int ob   = j0 % 3;
    int n    = tile >> 9;
    int hp   = (tile >> 2) & 127;
    int wseg = tile & 3;
    int w0 = wseg << 7, o0 = ob << 7, h0 = hp << 1;

    int tid = threadIdx.x;
    int lane = tid & 63;
    int wv = tid >> 6;
    int wr = wv >> 1, wc = wv & 1;
    int lo5 = lane & 31, hi = lane >> 5;

    // staging: 36 wave-issues per buffer, 9 per wave; per-lane global offsets
    int goff[9];
    #pragma unroll
    for (int it = 0; it < 9; ++it) {
        int k = wv * 9 + it;
        int plane = k / 18;
        int s = (k % 18) * 64 + lane;
        int r = s / 288;
        int rem = s - r * 288;
        int col = rem >> 1, h16 = rem & 1;
        goff[it] = plane * ICS16 + ((h0 + r) * PC + (w0 + col)) * 16 + h16 * 8;
    }

    const int KH[13] = {0,0,0,0,0,1,1,1,1,1,2,2,2};
    const int KW[13] = {0,1,2,3,4,0,1,2,3,4,0,1,2};

    f32x16 acc[4][2];
    #pragma unroll
    for (int pt = 0; pt < 4; ++pt)
        #pragma unroll
        for (int ot = 0; ot < 2; ++ot)
            #pragma unroll
            for (int r = 0; r < 16; ++r) acc[pt][ot][r] = 0.f;

    const unsigned short* gbase_n = in + (size_t)n * NKC * ICS16;

#define LOAD_XA(dst, u) do {                                              \
        int t_ = (u) >> 1, hf_ = (u) & 1;                                 \
        int so_ = hf_ * PLANE_SH + (wr + KH[t_]) * (TCOLS * 16)           \
                + (lo5 + KW[t_]) * 16 + hi * 8;                           \
        _Pragma("unroll")                                                 \
        for (int pt_ = 0; pt_ < 4; ++pt_)                                 \
            (dst)[pt_] = *(const short8*)&xs[so_ + pt_ * 512];            \
    } while (0)

#define LOAD_WB(dst, icc, u) do {                                         \
        int t_ = (u) >> 1, hf_ = (u) & 1;                                 \
        const unsigned short* wb_ = wp +                                  \
            (size_t)((t_ * NKC + (icc) * 2 + hf_) * C_CH + o0 + wc * 64) * 16; \
        _Pragma("unroll")                                                 \
        for (int ot_ = 0; ot_ < 2; ++ot_)                                 \
            (dst)[ot_] = *(const short8*)&wb_[(ot_ * 32 + lo5) * 16 + hi * 8]; \
    } while (0)

    short8 wb[2][2];
    // wb for (ic=0, u=0,1) issued FIRST: ahead of all staging in the vmcnt queue
    LOAD_WB(wb[0], 0, 0);
    LOAD_WB(wb[1], 0, 1);

    // prologue: stage ic=0 into buf 0
    #pragma unroll
    for (int it = 0; it < 9; ++it)
        __builtin_amdgcn_global_load_lds((gas_t)(gbase_n + goff[it]),
                                         (las_t)&Xs[0][(wv * 9 + it) * 512], 16, 0, 0);
    __syncthreads();

    for (int ic = 0; ic < 12; ++ic) {
        int buf = ic & 1;
        const unsigned short* xs = &Xs[buf][0];
        // stage next ic into other buffer (wb for steps 0,1 already issued earlier)
        if (ic < 11) {
            const unsigned short* gb = gbase_n + (size_t)(ic + 1) * 2 * ICS16;
            #pragma unroll
            for (int it = 0; it < 9; ++it)
                __builtin_amdgcn_global_load_lds((gas_t)(gb + goff[it]),
                                                 (las_t)&Xs[buf ^ 1][(wv * 9 + it) * 512], 16, 0, 0);
        }

        short8 xa[2][4];
        LOAD_XA(xa[0], 0);
        int icn = ic < 11 ? ic + 1 : 11;   // cross-ic wb prefetch target

        #pragma unroll
        for (int s2 = 0; s2 < 26; ++s2) {
            if (s2 + 1 < 26) LOAD_XA(xa[(s2 + 1) & 1], s2 + 1);
            // schedule-shaping barrier: clusters this block's ds_reads before it
            // and its MFMA octet after it, so the two co-resident blocks
            // anti-phase (one computes while the other reads). Guards no data
            // (LDS buffers are read-only within an ic) -> zero correctness risk.
            __builtin_amdgcn_s_barrier();
            __builtin_amdgcn_s_setprio(1);
            #pragma unroll
            for (int pt = 0; pt < 4; ++pt)
                #pragma unroll
                for (int ot = 0; ot < 2; ++ot) {
                    if (SECOND)
                        acc[pt][ot] = __builtin_amdgcn_mfma_f32_32x32x16_bf16(
                            wb[s2 & 1][ot], xa[s2 & 1][pt], acc[pt][ot], 0, 0, 0);
                    else
                        acc[pt][ot] = __builtin_amdgcn_mfma_f32_32x32x16_bf16(
                            xa[s2 & 1][pt], wb[s2 & 1][ot], acc[pt][ot], 0, 0, 0);
                }
            __builtin_amdgcn_s_setprio(0);
            // consume-then-prefetch: refill the slot just used with u = s2+2
            // (steps 24,25 fetch NEXT ic's u=0,1 -> issued before next stage block)
            if (s2 + 2 < 26) {
                LOAD_WB(wb[s2 & 1], ic, s2 + 2);
            } else {
                LOAD_WB(wb[s2 & 1], icn, s2 - 24);
            }
        }
        __syncthreads();
    }
#undef LOAD_XA
#undef LOAD_WB

    int h = h0 + wr;
    if (!SECOND) {
        // D[p][o]: p = pt*32 + (reg&3)+8*(reg>>2)+4*hi ; o = o0+wc*64+ot*32+lo5
        unsigned short* y = (unsigned short*)outp;
        #pragma unroll
        for (int ot = 0; ot < 2; ++ot) {
            int o = o0 + wc * 64 + ot * 32 + lo5;
            float bo = bias[o], ao = alpha[o];
            int kc = o >> 4;
            int o15 = o & 15;
            size_t base = (size_t)(n * NKC + kc) * ICS16 + ((h + 2) * PC + (w0 + 2)) * 16 + o15;
            #pragma unroll
            for (int pt = 0; pt < 4; ++pt) {
                #pragma unroll
                for (int reg = 0; reg < 16; ++reg) {
                    int p = pt * 32 + (reg & 3) + 8 * (reg >> 2) + 4 * hi;
                    float v = acc[pt][ot][reg] + bo;
                    v = v >= 0.f ? v : ao * v;
                    y[base + (size_t)p * 16] = f2bf(v);
                }
            }
        }
    } else {
        // D[o][p]: o = o0+wc*64+ot*32+(reg&3)+8*(reg>>2)+4*hi ; w = w0+pt*32+lo5
        float* outf = (float*)outp;
        #pragma unroll
        for (int ot = 0; ot < 2; ++ot) {
            #pragma unroll
            for (int reg = 0; reg < 16; ++reg) {
                int o = o0 + wc * 64 + ot * 32 + (reg & 3) + 8 * (reg >> 2) + 4 * hi;
                float bo = bias[o], ao = alpha[o];
                #pragma unroll
                for (int pt = 0; pt < 4; ++pt) {
                    int w = w0 + pt * 32 + lo5;
                    float v = acc[pt][ot][reg] + bo;
                    v = v >= 0.f ? v : ao * v;
                    size_t idx = (size_t)((n * C_CH + o) * HH + h) * WWD + w;
                    outf[idx] = v + xres[idx];
                }
            }
        }
    }
}

extern "C" void kernel_launch(void* const* d_in, const int* in_sizes, int n_in,
                              void* d_out, int out_size, void* d_ws, size_t ws_size,
                              hipStream_t stream) {
    const float* x  = (const float*)d_in[0];
    const float* w1 = (const float*)d_in[1];
    const float* b1 = (const float*)d_in[2];
    const float* a1 = (const float*)d_in[3];
    const float* w2 = (const float*)d_in[4];
    const float* b2 = (const float*)d_in[5];
    const float* a2 = (const float*)d_in[6];

    const size_t PLANE_SHORTS = (size_t)NN * NKC * ICS16;       // 103,034,880 shorts
    unsigned short* xc  = (unsigned short*)d_out;               // 206,069,760 B scratch in d_out
    unsigned short* yb  = (unsigned short*)d_ws;                // 206,069,760 B
    unsigned short* wp1 = yb + PLANE_SHORTS;                    // 3,833,856 B
    unsigned short* wp2 = wp1 + 13 * NKC * C_CH * 16;           // 3,833,856 B

    k_prepack<<<(13 * NKC * C_CH * 16 + 255) / 256, 256, 0, stream>>>(w1, w2, wp1, wp2);
    k_zero_halo<<<NN * NKC, 256, 0, stream>>>(xc, yb);
    k_repack_x<<<NN * HH * (WWD / 64), 256, 0, stream>>>(x, xc);
    k_conv<0><<<3072, 256, 0, stream>>>(xc, wp1, b1, a1, nullptr, (void*)yb);
    k_conv<1><<<3072, 256, 0, stream>>>(yb, wp2, b2, a2, x, (void*)d_out);
}